// Round 1
// 729.045 us; speedup vs baseline: 1.0034x; 1.0034x over previous
//
#include <hip/hip_runtime.h>
#include <hip/hip_cooperative_groups.h>

namespace cg = cooperative_groups;

#define N_PTS 131072
#define NSEG 128
#define SW 132        // LDS row stride in u16 (128 + 4 pad)
#define PSTRIDE 33024 // floats per stats parity: Z(128)+W(128)+M(16384)+Q(16384)

typedef unsigned short u16;
typedef __attribute__((ext_vector_type(8))) short short8;
typedef __attribute__((ext_vector_type(8))) unsigned short ushort8;
typedef __attribute__((ext_vector_type(4))) float f32x4;

__device__ __forceinline__ float b2f(u16 u){union{unsigned v;float f;}x;x.v=((unsigned)u)<<16;return x.f;}
__device__ __forceinline__ u16 f2b(float f){unsigned u=__float_as_uint(f);u+=0x7FFFu+((u>>16)&1u);return (u16)(u>>16);}
// agent-scope (device) coherent helpers: stats cross XCDs inside the fused kernel,
// per-XCD L2 is not coherent -> bypass it for stats traffic.
__device__ __forceinline__ float aload(const float* p){ return __hip_atomic_load(p, __ATOMIC_RELAXED, __HIP_MEMORY_SCOPE_AGENT); }
__device__ __forceinline__ void astore(float* p, float v){ __hip_atomic_store(p, v, __ATOMIC_RELAXED, __HIP_MEMORY_SCOPE_AGENT); }

// ======================================================================
// pack 18 matrices transposed bf16 + fold attW: u[l][k]=sum_c bf16W[k][c]*attW[c], c0=b·attW+attb
__global__ __launch_bounds__(256) void k_wpack(const float* __restrict__ Wr,
    const float* __restrict__ convW, const float* __restrict__ outW,
    const float* __restrict__ attW, const float* __restrict__ attb,
    const float* __restrict__ convb,
    u16* __restrict__ Wf, float* __restrict__ uAtt, float* __restrict__ cAtt){
  int mat = blockIdx.x;
  const float* W = (mat<4) ? (Wr+mat*16384) : (mat<16) ? (convW+(mat-4)*16384) : (outW+(mat-16)*16384);
  u16* dst = Wf + mat*16384;
  for (int t = threadIdx.x; t < 16384; t += 256){ int n=t>>7,k=t&127; dst[t]=f2b(W[k*128+n]); }
  if (mat>=4 && mat<16){
    int l = mat-4;
    __syncthreads();
    int tid = threadIdx.x;
    if (tid < 128){
      float s = 0.f;
      for (int c=0;c<128;c++) s += b2f(dst[c*128+tid]) * attW[l*128+c];
      uAtt[l*128+tid] = s;
    } else if (tid == 128){
      float s = attb[l];
      for (int c=0;c<128;c++) s += convb[l*128+c] * attW[l*128+c];
      cAtt[l] = s;
    }
  }
}

// ======================================================================
// In-place GEMM over the 128x128 LDS tile with lrelu epilogue.
// Per rt-slab: all waves read slab rt -> barrier -> write slab rt.  Caller
// must __syncthreads() after the call before re-reading Xs.
__device__ __forceinline__ void gemm_lrelu_inplace(u16* Xs, const u16* __restrict__ Wm,
    const float* __restrict__ Bv, int wave, int q, int m16){
  short8 bfr[2][4];
  const int cA = wave*32 + 2*m16;
  #pragma unroll
  for (int ct=0; ct<2; ct++){
    int n = cA + ct;
    #pragma unroll
    for (int kc=0; kc<4; kc++) bfr[ct][kc] = *(const short8*)&Wm[n*128 + kc*32 + q*8];
  }
  const float b0 = Bv[cA], b1 = Bv[cA+1];
  #pragma unroll
  for (int rt=0; rt<8; rt++){
    const int r0 = rt*16;
    f32x4 a0={0,0,0,0}, a1={0,0,0,0};
    short8 afn = *(const short8*)&Xs[(r0+m16)*SW + q*8];
    #pragma unroll
    for (int kc=0; kc<4; kc++){
      short8 afc = afn;
      if (kc<3) afn = *(const short8*)&Xs[(r0+m16)*SW + (kc+1)*32 + q*8];
      a0 = __builtin_amdgcn_mfma_f32_16x16x32_bf16(afc, bfr[0][kc], a0, 0,0,0);
      a1 = __builtin_amdgcn_mfma_f32_16x16x32_bf16(afc, bfr[1][kc], a1, 0,0,0);
    }
    __syncthreads();   // all reads of slab rt complete
    #pragma unroll
    for (int t=0; t<4; t++){
      int rloc = r0 + q*4 + t;
      float v0 = a0[t]+b0, v1 = a1[t]+b1;
      v0 = v0>0.f ? v0 : 0.01f*v0;
      v1 = v1>0.f ? v1 : 0.01f*v1;
      *(unsigned*)&Xs[rloc*SW + cA] = (unsigned)f2b(v0) | ((unsigned)f2b(v1)<<16);
    }
  }
}

// ======================================================================
// Fully-fused persistent network: in0 + 4 MLP + 12 conv/ACN + out MLP.
// 1024 blocks x 256 threads, 4 blocks/CU co-resident (cooperative launch).
// Activations live in LDS (Xs); residual h lives in 64 VGPRs/thread.
__global__ __launch_bounds__(256, 4) void k_fused(
    const float* __restrict__ x, const int* __restrict__ seg, const float* __restrict__ wp,
    const float* __restrict__ Win0, const float* __restrict__ bin0,
    const float* __restrict__ br, const float* __restrict__ convb, const float* __restrict__ outb,
    const u16* __restrict__ Wf, const float* __restrict__ uAtt, const float* __restrict__ cAtt,
    float* __restrict__ Pstat, float* __restrict__ Of, float* __restrict__ a_out)
{
  __shared__ u16 Xs[128*SW];       // 33792 B
  __shared__ float rowP[128];
  __shared__ float eS[128], aS[128];
  __shared__ int   sgS[128];
  __shared__ float wpS[128];
  __shared__ float MhL[2][128], ScL[2][128];   // per-(seg,ch) shift/scale

  const int tid=threadIdx.x, wave=tid>>6, lane=tid&63, q=lane>>4, m16=lane&15;
  const int row0=blockIdx.x*128;
  const int c8=(tid*8)&127;
  const int rbase=tid>>4;          // staging row within 16-row stripe

  cg::grid_group grid = cg::this_grid();

  if (tid<128){ sgS[tid]=seg[row0+tid]; wpS[tid]=wp[row0+tid]; }
  // zero stats parity 0 (33 floats per block covers 33024)
  if (tid<33){ int idx=blockIdx.x*33+tid; if (idx<PSTRIDE) astore(Pstat+idx, 0.f); }
  __syncthreads();

  const int sA=sgS[0], sB=sgS[127];
  const bool uni=(sA==sB);
  // per-thread slot bit per staged stripe (sorted segs => <=2 segs per 128-row block)
  unsigned slotm=0;
  #pragma unroll
  for (int i=0;i<8;i++) if (sgS[i*16+rbase]!=sA) slotm|=1u<<i;

  // ---- input layer: Xs = bf16(lrelu(x @ W0 + b0)) ----
  {
    float w0[8],w1[8],w2[8],bv[8];
    *(float4*)&w0[0]=*(const float4*)&Win0[c8];     *(float4*)&w0[4]=*(const float4*)&Win0[c8+4];
    *(float4*)&w1[0]=*(const float4*)&Win0[128+c8]; *(float4*)&w1[4]=*(const float4*)&Win0[128+c8+4];
    *(float4*)&w2[0]=*(const float4*)&Win0[256+c8]; *(float4*)&w2[4]=*(const float4*)&Win0[256+c8+4];
    *(float4*)&bv[0]=*(const float4*)&bin0[c8];     *(float4*)&bv[4]=*(const float4*)&bin0[c8+4];
    #pragma unroll
    for (int i=0;i<8;i++){
      int rloc=i*16+rbase, r=row0+rloc;
      float x0=x[r*3], x1=x[r*3+1], x2=x[r*3+2];
      ushort8 ob;
      #pragma unroll
      for (int jj=0;jj<8;jj++){
        float v=bv[jj]+x0*w0[jj]+x1*w1[jj]+x2*w2[jj];
        v=v>0.f?v:0.01f*v;
        ob[jj]=f2b(v);
      }
      *(ushort8*)&Xs[rloc*SW+c8]=ob;
    }
  }
  __syncthreads();

  // ---- 4 MLP layers (in-place, lrelu) ----
  #pragma unroll 1
  for (int l=0;l<4;l++){
    gemm_lrelu_inplace(Xs, Wf + (size_t)l*16384, br + l*128, wave,q,m16);
    __syncthreads();
  }

  grid.sync();   // parity-0 zeros visible everywhere before layer-0 atomics

  float h[64];   // residual stream, fp32, staging layout h[i*8+jj]

  // ---- 12 conv/ACN layers ----
  #pragma unroll 1
  for (int j=0;j<12;j++){
    float* Pw = Pstat + (j%3)*PSTRIDE;         // written this layer
    const float* Pr = Pstat + ((j+2)%3)*PSTRIDE; // stats from layer j-1
    float* Pn = Pstat + ((j+1)%3)*PSTRIDE;     // zeroed for layer j+1

    // per-(seg,ch) shift/scale once per layer (not per element)
    if (j>0){
      int half=tid>>7, ch=tid&127;
      int s = half ? sB : sA;
      float Z=aload(Pr+s), Wd=aload(Pr+128+s);
      float invd=1.f/fmaxf(Wd, fmaxf(1e-3f*Z, 1e-30f));
      float sa=Wd*invd;
      float m =aload(Pr+256  + s*128+ch)*invd;
      float qv=aload(Pr+16640+ s*128+ch)*invd;
      MhL[half][ch]=m;
      ScL[half][ch]=rsqrtf(qv+(sa-2.f)*m*m+1e-3f);
    }
    float uv[8];
    { float4 u0=*(const float4*)&uAtt[j*128+c8]; float4 u1=*(const float4*)&uAtt[j*128+c8+4];
      uv[0]=u0.x;uv[1]=u0.y;uv[2]=u0.z;uv[3]=u0.w;uv[4]=u1.x;uv[5]=u1.y;uv[6]=u1.z;uv[7]=u1.w; }
    const float cL0 = cAtt[j];
    __syncthreads();   // MhL/ScL ready

    // staging: normalize(+relu)(+residual) in place + logit partials
    #pragma unroll
    for (int i=0;i<8;i++){
      const int rloc=i*16+rbase;
      ushort8 raw=*(const ushort8*)&Xs[rloc*SW+c8];
      float v[8];
      if (j==0){
        #pragma unroll
        for (int jj=0;jj<8;jj++){ v[jj]=b2f(raw[jj]); h[i*8+jj]=v[jj]; }
        // values unchanged; no rewrite needed
      } else {
        const int sl=(slotm>>i)&1;
        #pragma unroll
        for (int jj=0;jj<8;jj++){
          float vv=(b2f(raw[jj])-MhL[sl][c8+jj])*ScL[sl][c8+jj];
          vv=fmaxf(vv,0.f);
          if ((j&1)==0){ vv+=h[i*8+jj]; h[i*8+jj]=vv; }   // even j>0: residual add + h update
          v[jj]=vv;
        }
        ushort8 ob;
        #pragma unroll
        for (int jj=0;jj<8;jj++) ob[jj]=f2b(v[jj]);
        *(ushort8*)&Xs[rloc*SW+c8]=ob;
      }
      float p = v[0]*uv[0]+v[1]*uv[1]+v[2]*uv[2]+v[3]*uv[3]
              + v[4]*uv[4]+v[5]*uv[5]+v[6]*uv[6]+v[7]*uv[7];
      p += __shfl_xor(p,1,64); p += __shfl_xor(p,2,64);
      p += __shfl_xor(p,4,64); p += __shfl_xor(p,8,64);
      if (m16==0) rowP[rloc]=p;
    }
    __syncthreads();   // Xs + rowP ready

    if (tid<128){
      float l2=rowP[tid]+cL0;
      float e=__expf(fminf(l2,60.f));   // logits O(1); clamp = overflow guard
      float sw=e*wpS[tid];
      eS[tid]=e; aS[tid]=sw;
    }
    // zero next parity (idle this layer)
    if (tid<33){ int idx=blockIdx.x*33+tid; if (idx<PSTRIDE) astore(Pn+idx, 0.f); }
    __syncthreads();   // eS/aS ready
    if (tid<128){
      int s=sgS[tid];
      if (tid==0 || sgS[tid-1]!=s){     // run leader (1-2 per block)
        float se=0.f, ss=0.f;
        for (int i2=tid;i2<128 && sgS[i2]==s;i2++){ se+=eS[i2]; ss+=aS[i2]; }
        atomicAdd(&Pw[s],se); atomicAdd(&Pw[128+s],ss);
      }
    }

    // GEMM (in-place, raw y+bias written back) + channel-stats accumulation
    const u16* Wm = Wf + (size_t)(4+j)*16384;
    const float* Bv = convb + j*128;
    short8 bfr[2][4];
    const int cA = wave*32+2*m16;
    #pragma unroll
    for (int ct=0;ct<2;ct++){
      int n=cA+ct;
      #pragma unroll
      for (int kc=0;kc<4;kc++) bfr[ct][kc]=*(const short8*)&Wm[n*128+kc*32+q*8];
    }
    const float bias0=Bv[cA], bias1=Bv[cA+1];
    float* cM=Pw+256; float* cQ=Pw+16640;
    int cur = uni ? sA : sgS[q*4];
    float sx0=0.f,sq0=0.f,sx1=0.f,sq1=0.f;
    #pragma unroll
    for (int rt=0;rt<8;rt++){
      const int r0=rt*16;
      f32x4 a0={0,0,0,0}, a1={0,0,0,0};
      short8 afn=*(const short8*)&Xs[(r0+m16)*SW+q*8];
      #pragma unroll
      for (int kc=0;kc<4;kc++){
        short8 afc=afn;
        if (kc<3) afn=*(const short8*)&Xs[(r0+m16)*SW+(kc+1)*32+q*8];
        a0=__builtin_amdgcn_mfma_f32_16x16x32_bf16(afc,bfr[0][kc],a0,0,0,0);
        a1=__builtin_amdgcn_mfma_f32_16x16x32_bf16(afc,bfr[1][kc],a1,0,0,0);
      }
      __syncthreads();   // all reads of slab rt done -> safe to overwrite
      #pragma unroll
      for (int t=0;t<4;t++){
        int rloc=r0+q*4+t;
        float v0=a0[t]+bias0, v1=a1[t]+bias1;
        *(unsigned*)&Xs[rloc*SW+cA]=(unsigned)f2b(v0)|((unsigned)f2b(v1)<<16);
        float a=aS[rloc];
        if (!uni){
          int s=sgS[rloc];
          if (s!=cur){
            atomicAdd(&cM[cur*128+cA],sx0);  atomicAdd(&cQ[cur*128+cA],sq0);
            atomicAdd(&cM[cur*128+cA+1],sx1);atomicAdd(&cQ[cur*128+cA+1],sq1);
            sx0=sq0=sx1=sq1=0.f; cur=s;
          }
        }
        sx0+=a*v0; sq0+=a*v0*v0; sx1+=a*v1; sq1+=a*v1*v1;
      }
    }
    if (uni){
      sx0+=__shfl_xor(sx0,16,64); sx0+=__shfl_xor(sx0,32,64);
      sq0+=__shfl_xor(sq0,16,64); sq0+=__shfl_xor(sq0,32,64);
      sx1+=__shfl_xor(sx1,16,64); sx1+=__shfl_xor(sx1,32,64);
      sq1+=__shfl_xor(sq1,16,64); sq1+=__shfl_xor(sq1,32,64);
      if (q==0){
        atomicAdd(&cM[sA*128+cA],sx0);  atomicAdd(&cQ[sA*128+cA],sq0);
        atomicAdd(&cM[sA*128+cA+1],sx1);atomicAdd(&cQ[sA*128+cA+1],sq1);
      }
    } else {
      atomicAdd(&cM[cur*128+cA],sx0);  atomicAdd(&cQ[cur*128+cA],sq0);
      atomicAdd(&cM[cur*128+cA+1],sx1);atomicAdd(&cQ[cur*128+cA+1],sq1);
    }
    grid.sync();   // stats j complete + visible; LDS writes complete
  }

  // ---- output: norm+res + out0(lrelu) + out1 -> Of; a_out ----
  {
    const float* Pr = Pstat + 2*PSTRIDE;   // layer-11 stats (11%3==2)
    { int half=tid>>7, ch=tid&127;
      int s = half ? sB : sA;
      float Z=aload(Pr+s), Wd=aload(Pr+128+s);
      float invd=1.f/fmaxf(Wd, fmaxf(1e-3f*Z, 1e-30f));
      float sa=Wd*invd;
      float m =aload(Pr+256  + s*128+ch)*invd;
      float qv=aload(Pr+16640+ s*128+ch)*invd;
      MhL[half][ch]=m;
      ScL[half][ch]=rsqrtf(qv+(sa-2.f)*m*m+1e-3f);
    }
    if (tid<128){
      int s=sgS[tid];
      float Z=aload(Pr+s), Wd=aload(Pr+128+s);
      float invd=1.f/fmaxf(Wd, fmaxf(1e-3f*Z, 1e-30f));
      a_out[row0+tid]=aS[tid]*invd;   // aS still holds layer-11 e*wp
    }
    __syncthreads();
    #pragma unroll
    for (int i=0;i<8;i++){
      const int rloc=i*16+rbase;
      ushort8 raw=*(const ushort8*)&Xs[rloc*SW+c8];
      const int sl=(slotm>>i)&1;
      ushort8 ob;
      #pragma unroll
      for (int jj=0;jj<8;jj++){
        float vv=(b2f(raw[jj])-MhL[sl][c8+jj])*ScL[sl][c8+jj];
        vv=fmaxf(vv,0.f)+h[i*8+jj];
        ob[jj]=f2b(vv);
      }
      *(ushort8*)&Xs[rloc*SW+c8]=ob;
    }
    __syncthreads();
    gemm_lrelu_inplace(Xs, Wf+(size_t)16*16384, outb, wave,q,m16);
    __syncthreads();
    // out1: reads Xs, writes Of directly (no in-place write -> no inner barrier)
    {
      const u16* Wm=Wf+(size_t)17*16384;
      short8 bfr[2][4];
      const int cA=wave*32+2*m16;
      #pragma unroll
      for (int ct=0;ct<2;ct++){
        int n=cA+ct;
        #pragma unroll
        for (int kc=0;kc<4;kc++) bfr[ct][kc]=*(const short8*)&Wm[n*128+kc*32+q*8];
      }
      const float b0=outb[128+cA], b1=outb[128+cA+1];
      #pragma unroll
      for (int rt=0;rt<8;rt++){
        const int r0=rt*16;
        f32x4 a0={0,0,0,0}, a1={0,0,0,0};
        short8 afn=*(const short8*)&Xs[(r0+m16)*SW+q*8];
        #pragma unroll
        for (int kc=0;kc<4;kc++){
          short8 afc=afn;
          if (kc<3) afn=*(const short8*)&Xs[(r0+m16)*SW+(kc+1)*32+q*8];
          a0=__builtin_amdgcn_mfma_f32_16x16x32_bf16(afc,bfr[0][kc],a0,0,0,0);
          a1=__builtin_amdgcn_mfma_f32_16x16x32_bf16(afc,bfr[1][kc],a1,0,0,0);
        }
        #pragma unroll
        for (int t=0;t<4;t++){
          int rloc=r0+q*4+t;
          float2 o={a0[t]+b0, a1[t]+b1};
          ((float2*)Of)[(size_t)(row0+rloc)*64 + wave*16 + m16]=o;
        }
      }
    }
  }
}

// ======================================================================
// ===================== FALLBACK PATH (verified 731us) =================
// ======================================================================
__global__ __launch_bounds__(256) void k_zero(float* __restrict__ M0, float* __restrict__ Q0,
                                              float* __restrict__ Z0, float* __restrict__ W0){
  int t = blockIdx.x * 256 + threadIdx.x;
  M0[t] = 0.f; Q0[t] = 0.f;
  if (t < 128) { Z0[t] = 0.f; W0[t] = 0.f; }
}

__global__ __launch_bounds__(256) void k_in0(const float* __restrict__ x,
    const float* __restrict__ W0, const float* __restrict__ b0, u16* __restrict__ Tb){
  int gid = blockIdx.x*256 + threadIdx.x;
  int n = gid>>7, c = gid&127;
  float acc = b0[c] + x[n*3]*W0[c] + x[n*3+1]*W0[128+c] + x[n*3+2]*W0[256+c];
  Tb[gid] = f2b(acc > 0.f ? acc : 0.01f*acc);
}

template<bool WH>
__global__ __launch_bounds__(256) void k_mlp(u16* __restrict__ Tb, float* __restrict__ A0,
    const u16* __restrict__ Wfm, const float* __restrict__ Bv){
  __shared__ u16 Xs[128*SW];
  const int tid=threadIdx.x, wave=tid>>6, lane=tid&63, q=lane>>4, m16=lane&15;
  const int row0=blockIdx.x*128;
  const u16* Xb = Tb + (size_t)row0*128;
  #pragma unroll
  for (int i=0;i<8;i++){
    int e8=i*2048+tid*8; int rloc=e8>>7, c8=e8&127;
    *(ushort8*)&Xs[rloc*SW+c8] = *(const ushort8*)&Xb[rloc*128+c8];
  }
  short8 bfr[2][4];
  #pragma unroll
  for (int ct=0;ct<2;ct++){
    int n = wave*32 + 2*m16 + ct;
    #pragma unroll
    for (int kc=0;kc<4;kc++) bfr[ct][kc] = *(const short8*)&Wfm[n*128+kc*32+q*8];
  }
  const int cA = wave*32 + 2*m16;
  const float bias0=Bv[cA], bias1=Bv[cA+1];
  __syncthreads();
  #pragma unroll
  for (int rt=0;rt<8;rt++){
    int r0=rt*16;
    short8 af[4];
    #pragma unroll
    for (int kc=0;kc<4;kc++) af[kc] = *(const short8*)&Xs[(r0+m16)*SW+kc*32+q*8];
    f32x4 a0={0,0,0,0}, a1={0,0,0,0};
    #pragma unroll
    for (int kc=0;kc<4;kc++){
      a0=__builtin_amdgcn_mfma_f32_16x16x32_bf16(af[kc],bfr[0][kc],a0,0,0,0);
      a1=__builtin_amdgcn_mfma_f32_16x16x32_bf16(af[kc],bfr[1][kc],a1,0,0,0);
    }
    #pragma unroll
    for (int t=0;t<4;t++){
      int rloc=r0+q*4+t;
      float v0=a0[t]+bias0, v1=a1[t]+bias1;
      v0=v0>0.f?v0:0.01f*v0; v1=v1>0.f?v1:0.01f*v1;
      size_t wi=(size_t)(row0+rloc)*64 + wave*16 + m16;
      ((unsigned*)Tb)[wi] = (unsigned)f2b(v0) | ((unsigned)f2b(v1)<<16);
      if (WH) { float2 hh={v0,v1}; ((float2*)A0)[wi]=hh; }
    }
  }
}

template<int IN>
__global__ __launch_bounds__(256) void k_conv(u16* __restrict__ Tb, float* __restrict__ A0,
    const u16* __restrict__ Wfm, const float* __restrict__ Bv,
    const float* __restrict__ uL, const float* __restrict__ cL,
    float* __restrict__ L, const int* __restrict__ seg, const float* __restrict__ wpv,
    const float* __restrict__ pZ, const float* __restrict__ pW,
    const float* __restrict__ pM, const float* __restrict__ pQ,
    float* __restrict__ cZ, float* __restrict__ cW,
    float* __restrict__ cM, float* __restrict__ cQ,
    float* __restrict__ nZ, float* __restrict__ nW,
    float* __restrict__ nM, float* __restrict__ nQ){
  __shared__ u16 Xs[128*SW];
  __shared__ float rowP[128];
  __shared__ float eS[128], aS[128];
  __shared__ int sgS[128];
  const int tid=threadIdx.x, wave=tid>>6, lane=tid&63, q=lane>>4, m16=lane&15;
  const int row0=blockIdx.x*128;

  if (tid<16){ nM[blockIdx.x*16+tid]=0.f; nQ[blockIdx.x*16+tid]=0.f; }
  if (blockIdx.x==0 && tid<128){ nZ[tid]=0.f; nW[tid]=0.f; }

  const int c8 = (tid*8)&127;
  float uv[8];
  { float4 u0=*(const float4*)&uL[c8]; float4 u1=*(const float4*)&uL[c8+4];
    uv[0]=u0.x;uv[1]=u0.y;uv[2]=u0.z;uv[3]=u0.w;uv[4]=u1.x;uv[5]=u1.y;uv[6]=u1.z;uv[7]=u1.w; }

  const u16* Xb = Tb + (size_t)row0*128;
  #pragma unroll
  for (int i=0;i<8;i++){
    int rloc = i*16 + (tid>>4);
    ushort8 raw = *(const ushort8*)&Xb[rloc*128+c8];
    float v[8];
    if (IN==1){
      #pragma unroll
      for (int j=0;j<8;j++) v[j]=b2f(raw[j]);
      *(ushort8*)&Xs[rloc*SW+c8] = raw;
    } else {
      int gr=row0+rloc, s=seg[gr];
      float Z=pZ[s], Wd=pW[s];
      float invd = 1.f/fmaxf(Wd, fmaxf(1e-3f*Z, 1e-30f));
      float sa = Wd*invd;
      float4 mn0=*(const float4*)&pM[s*128+c8];
      float4 mn1=*(const float4*)&pM[s*128+c8+4];
      float4 q0=*(const float4*)&pQ[s*128+c8];
      float4 q1=*(const float4*)&pQ[s*128+c8+4];
      float mn[8]={mn0.x,mn0.y,mn0.z,mn0.w,mn1.x,mn1.y,mn1.z,mn1.w};
      float qv[8]={q0.x,q0.y,q0.z,q0.w,q1.x,q1.y,q1.z,q1.w};
      #pragma unroll
      for (int j=0;j<8;j++){
        float m=mn[j]*invd, m2=qv[j]*invd;
        v[j]=fmaxf((b2f(raw[j])-m)*rsqrtf(m2+(sa-2.f)*m*m+1e-3f),0.f);
      }
      if (IN==3){
        float4 h0=*(const float4*)&A0[(size_t)gr*128+c8];
        float4 h1=*(const float4*)&A0[(size_t)gr*128+c8+4];
        v[0]+=h0.x;v[1]+=h0.y;v[2]+=h0.z;v[3]+=h0.w;
        v[4]+=h1.x;v[5]+=h1.y;v[6]+=h1.z;v[7]+=h1.w;
        float4 w0={v[0],v[1],v[2],v[3]}, w1={v[4],v[5],v[6],v[7]};
        *(float4*)&A0[(size_t)gr*128+c8]=w0;
        *(float4*)&A0[(size_t)gr*128+c8+4]=w1;
      }
      ushort8 ob;
      #pragma unroll
      for (int j=0;j<8;j++) ob[j]=f2b(v[j]);
      *(ushort8*)&Xs[rloc*SW+c8]=ob;
    }
    float p = v[0]*uv[0]+v[1]*uv[1]+v[2]*uv[2]+v[3]*uv[3]
            + v[4]*uv[4]+v[5]*uv[5]+v[6]*uv[6]+v[7]*uv[7];
    p += __shfl_xor(p,1,64); p += __shfl_xor(p,2,64);
    p += __shfl_xor(p,4,64); p += __shfl_xor(p,8,64);
    if (m16==0) rowP[rloc]=p;
  }

  short8 bfr[2][4];
  #pragma unroll
  for (int ct=0;ct<2;ct++){
    int n = wave*32 + 2*m16 + ct;
    #pragma unroll
    for (int kc=0;kc<4;kc++) bfr[ct][kc]=*(const short8*)&Wfm[n*128+kc*32+q*8];
  }
  const int cA = wave*32 + 2*m16;
  const float bias0=Bv[cA], bias1=Bv[cA+1];
  __syncthreads();

  if (tid<128){
    int r=row0+tid;
    float l=rowP[tid]+cL[0];
    float e=__expf(fminf(l,60.f));
    float sw=e*wpv[r];
    L[r]=sw;
    eS[tid]=e; aS[tid]=sw; sgS[tid]=seg[r];
  }
  __syncthreads();
  if (tid<128){
    int s=sgS[tid];
    if (tid==0 || sgS[tid-1]!=s){
      float se=0.f, ss=0.f;
      for (int i=tid;i<128 && sgS[i]==s;i++){ se+=eS[i]; ss+=aS[i]; }
      atomicAdd(&cZ[s],se); atomicAdd(&cW[s],ss);
    }
  }

  const int s0=sgS[0], s127=sgS[127];
  const bool uni = (s0==s127);
  int cur = uni ? s0 : sgS[q*4];
  float sx0=0.f,sq0=0.f,sx1=0.f,sq1=0.f;

  #pragma unroll
  for (int rt=0;rt<8;rt++){
    int r0=rt*16;
    short8 af[4];
    #pragma unroll
    for (int kc=0;kc<4;kc++) af[kc]=*(const short8*)&Xs[(r0+m16)*SW+kc*32+q*8];
    f32x4 a0={0,0,0,0}, a1={0,0,0,0};
    #pragma unroll
    for (int kc=0;kc<4;kc++){
      a0=__builtin_amdgcn_mfma_f32_16x16x32_bf16(af[kc],bfr[0][kc],a0,0,0,0);
      a1=__builtin_amdgcn_mfma_f32_16x16x32_bf16(af[kc],bfr[1][kc],a1,0,0,0);
    }
    #pragma unroll
    for (int t=0;t<4;t++){
      int rloc=r0+q*4+t;
      float v0=a0[t]+bias0, v1=a1[t]+bias1;
      ((unsigned*)Tb)[(size_t)(row0+rloc)*64 + wave*16 + m16] =
          (unsigned)f2b(v0) | ((unsigned)f2b(v1)<<16);
      float a = aS[rloc];
      if (!uni){
        int s = sgS[rloc];
        if (s != cur){
          atomicAdd(&cM[cur*128+cA],sx0);  atomicAdd(&cQ[cur*128+cA],sq0);
          atomicAdd(&cM[cur*128+cA+1],sx1);atomicAdd(&cQ[cur*128+cA+1],sq1);
          sx0=sq0=sx1=sq1=0.f; cur=s;
        }
      }
      sx0 += a*v0; sq0 += a*v0*v0;
      sx1 += a*v1; sq1 += a*v1*v1;
    }
  }
  if (uni){
    sx0 += __shfl_xor(sx0,16,64); sx0 += __shfl_xor(sx0,32,64);
    sq0 += __shfl_xor(sq0,16,64); sq0 += __shfl_xor(sq0,32,64);
    sx1 += __shfl_xor(sx1,16,64); sx1 += __shfl_xor(sx1,32,64);
    sq1 += __shfl_xor(sq1,16,64); sq1 += __shfl_xor(sq1,32,64);
    if (q==0){
      atomicAdd(&cM[s0*128+cA],sx0);  atomicAdd(&cQ[s0*128+cA],sq0);
      atomicAdd(&cM[s0*128+cA+1],sx1);atomicAdd(&cQ[s0*128+cA+1],sq1);
    }
  } else {
    atomicAdd(&cM[cur*128+cA],sx0);  atomicAdd(&cQ[cur*128+cA],sq0);
    atomicAdd(&cM[cur*128+cA+1],sx1);atomicAdd(&cQ[cur*128+cA+1],sq1);
  }
}

__global__ __launch_bounds__(256) void k_megaout(const u16* __restrict__ Tb,
    const float* __restrict__ A0, const u16* __restrict__ Wf16, const float* __restrict__ outbv,
    const int* __restrict__ seg, const float* __restrict__ L,
    const float* __restrict__ pZ, const float* __restrict__ pW,
    const float* __restrict__ pM, const float* __restrict__ pQ,
    float* __restrict__ Of, float* __restrict__ a_out){
  __shared__ u16 buf[2*128*SW];
  const int tid=threadIdx.x, wave=tid>>6, lane=tid&63, q=lane>>4, m16=lane&15;
  const int row0=blockIdx.x*128;
  const u16* Xb = Tb + (size_t)row0*128;
  #pragma unroll
  for (int i=0;i<8;i++){
    int e8=i*2048+tid*8; int rloc=e8>>7, c8=e8&127;
    ushort8 raw=*(const ushort8*)&Xb[rloc*128+c8];
    int gr=row0+rloc, s=seg[gr];
    float Z=pZ[s], Wd=pW[s];
    float invd=1.f/fmaxf(Wd, fmaxf(1e-3f*Z,1e-30f));
    float sa=Wd*invd;
    float4 mn0=*(const float4*)&pM[s*128+c8];
    float4 mn1=*(const float4*)&pM[s*128+c8+4];
    float4 q0=*(const float4*)&pQ[s*128+c8];
    float4 q1=*(const float4*)&pQ[s*128+c8+4];
    float mn[8]={mn0.x,mn0.y,mn0.z,mn0.w,mn1.x,mn1.y,mn1.z,mn1.w};
    float qv[8]={q0.x,q0.y,q0.z,q0.w,q1.x,q1.y,q1.z,q1.w};
    float4 h0=*(const float4*)&A0[(size_t)gr*128+c8];
    float4 h1=*(const float4*)&A0[(size_t)gr*128+c8+4];
    float hv[8]={h0.x,h0.y,h0.z,h0.w,h1.x,h1.y,h1.z,h1.w};
    ushort8 ob;
    #pragma unroll
    for (int j=0;j<8;j++){
      float m=mn[j]*invd, m2=qv[j]*invd;
      ob[j]=f2b(fmaxf((b2f(raw[j])-m)*rsqrtf(m2+(sa-2.f)*m*m+1e-3f),0.f)+hv[j]);
    }
    *(ushort8*)&buf[rloc*SW+c8]=ob;
  }
  if (tid<128){
    int r=row0+tid, s=seg[r];
    float invd=1.f/fmaxf(pW[s], fmaxf(1e-3f*pZ[s],1e-30f));
    a_out[r]=L[r]*invd;
  }
  __syncthreads();
  const int cA=wave*32+2*m16;
  {
    u16* dst=buf+128*SW;
    short8 bfr[2][4];
    #pragma unroll
    for (int ct=0;ct<2;ct++){
      int n=wave*32+2*m16+ct;
      #pragma unroll
      for (int kc=0;kc<4;kc++) bfr[ct][kc]=*(const short8*)&Wf16[n*128+kc*32+q*8];
    }
    float bias0=outbv[cA], bias1=outbv[cA+1];
    #pragma unroll
    for (int rt=0;rt<8;rt++){
      int r0=rt*16;
      short8 af[4];
      #pragma unroll
      for (int kc=0;kc<4;kc++) af[kc]=*(const short8*)&buf[(r0+m16)*SW+kc*32+q*8];
      f32x4 a0={0,0,0,0}, a1={0,0,0,0};
      #pragma unroll
      for (int kc=0;kc<4;kc++){
        a0=__builtin_amdgcn_mfma_f32_16x16x32_bf16(af[kc],bfr[0][kc],a0,0,0,0);
        a1=__builtin_amdgcn_mfma_f32_16x16x32_bf16(af[kc],bfr[1][kc],a1,0,0,0);
      }
      #pragma unroll
      for (int t=0;t<4;t++){
        int rloc=r0+q*4+t;
        float v0=a0[t]+bias0, v1=a1[t]+bias1;
        v0=v0>0.f?v0:0.01f*v0; v1=v1>0.f?v1:0.01f*v1;
        dst[rloc*SW+cA]=f2b(v0);
        dst[rloc*SW+cA+1]=f2b(v1);
      }
    }
  }
  __syncthreads();
  {
    const u16* src=buf+128*SW;
    short8 bfr[2][4];
    #pragma unroll
    for (int ct=0;ct<2;ct++){
      int n=wave*32+2*m16+ct;
      #pragma unroll
      for (int kc=0;kc<4;kc++) bfr[ct][kc]=*(const short8*)&Wf16[16384+n*128+kc*32+q*8];
    }
    float bias0=outbv[128+cA], bias1=outbv[128+cA+1];
    #pragma unroll
    for (int rt=0;rt<8;rt++){
      int r0=rt*16;
      short8 af[4];
      #pragma unroll
      for (int kc=0;kc<4;kc++) af[kc]=*(const short8*)&src[(r0+m16)*SW+kc*32+q*8];
      f32x4 a0={0,0,0,0}, a1={0,0,0,0};
      #pragma unroll
      for (int kc=0;kc<4;kc++){
        a0=__builtin_amdgcn_mfma_f32_16x16x32_bf16(af[kc],bfr[0][kc],a0,0,0,0);
        a1=__builtin_amdgcn_mfma_f32_16x16x32_bf16(af[kc],bfr[1][kc],a1,0,0,0);
      }
      #pragma unroll
      for (int t=0;t<4;t++){
        int rloc=r0+q*4+t;
        float2 o={a0[t]+bias0, a1[t]+bias1};
        ((float2*)Of)[(size_t)(row0+rloc)*64 + wave*16 + m16]=o;
      }
    }
  }
}

// ======================================================================
extern "C" void kernel_launch(void* const* d_in, const int* in_sizes, int n_in,
                              void* d_out, int out_size, void* d_ws, size_t ws_size,
                              hipStream_t stream){
  (void)in_sizes; (void)n_in; (void)out_size; (void)ws_size;
  const float* x     = (const float*)d_in[0];
  const int*   seg   = (const int*)d_in[1];
  const float* wp    = (const float*)d_in[2];
  const float* Win0  = (const float*)d_in[3];
  const float* bin0  = (const float*)d_in[4];
  const float* Wr    = (const float*)d_in[5];
  const float* br    = (const float*)d_in[6];
  const float* convW = (const float*)d_in[7];
  const float* convb = (const float*)d_in[8];
  const float* attW  = (const float*)d_in[9];
  const float* attb  = (const float*)d_in[10];
  const float* outW  = (const float*)d_in[11];
  const float* outb  = (const float*)d_in[12];

  float* A0 = (float*)d_ws;                       // residual h fp32 (fallback only)
  u16*   Tb = (u16*)(A0 + (size_t)N_PTS*128);     // bf16 activations (fallback only)
  float* L  = (float*)(Tb + (size_t)N_PTS*128);   // e*wp per row (fallback only)
  float* base = L + N_PTS;                        // stats: 3 parities x PSTRIDE
  float* SZ[3], *SWt[3], *SM[3], *SQ[3];
  for (int p=0;p<3;p++){
    SZ[p]  = base + p*PSTRIDE;
    SWt[p] = SZ[p] + 128;
    SM[p]  = SWt[p] + 128;
    SQ[p]  = SM[p] + 16384;
  }
  float* uAtt = base + 3*PSTRIDE;                 // [12][128]
  float* cAtt = uAtt + 12*128;                    // [12]
  u16*   Wf   = (u16*)(cAtt + 16);

  float* Of    = (float*)d_out;
  float* a_out = (float*)d_out + (size_t)N_PTS*128;

  const int GB = N_PTS/128;   // 1024

  // one-time: can we co-schedule 1024 blocks (4/CU) for cooperative launch?
  static int coop = -1;
  if (coop < 0){
    int nb = 0;
    hipError_t e = hipOccupancyMaxActiveBlocksPerMultiprocessor(&nb, (const void*)k_fused, 256, 0);
    int ncu = 0, dev = 0;
    hipGetDevice(&dev);
    hipDeviceProp_t prop;
    if (hipGetDeviceProperties(&prop, dev) == hipSuccess) ncu = prop.multiProcessorCount;
    coop = (e == hipSuccess && ncu > 0 && nb * ncu >= GB) ? 1 : 0;
  }

  k_wpack<<<18,256,0,stream>>>(Wr, convW, outW, attW, attb, convb, Wf, uAtt, cAtt);

  if (coop){
    void* args[] = {(void*)&x,(void*)&seg,(void*)&wp,(void*)&Win0,(void*)&bin0,
                    (void*)&br,(void*)&convb,(void*)&outb,
                    (void*)&Wf,(void*)&uAtt,(void*)&cAtt,(void*)&base,
                    (void*)&Of,(void*)&a_out};
    hipLaunchCooperativeKernel((const void*)k_fused, dim3(GB), dim3(256), args, 0, stream);
    return;
  }

  // -------- fallback: previous verified multi-kernel path --------
  k_zero<<<64,256,0,stream>>>(SM[0],SQ[0],SZ[0],SWt[0]);
  k_in0<<<N_PTS*128/256,256,0,stream>>>(x, Win0, bin0, Tb);

  for (int i=0;i<3;i++)
    k_mlp<false><<<GB,256,0,stream>>>(Tb, nullptr, Wf+i*16384, br+i*128);
  k_mlp<true><<<GB,256,0,stream>>>(Tb, A0, Wf+3*16384, br+3*128);

  for (int j=0;j<12;j++){
    int wp_ = j%3, rp = (j+2)%3, np = (j+1)%3;
    const u16* Wm = Wf + (size_t)(4+j)*16384;
    const float* uj = uAtt + j*128;
    const float* cj = cAtt + j;
    if (j==0)
      k_conv<1><<<GB,256,0,stream>>>(Tb, nullptr, Wm, convb, uj, cj, L, seg, wp,
          nullptr,nullptr,nullptr,nullptr,
          SZ[wp_],SWt[wp_],SM[wp_],SQ[wp_], SZ[np],SWt[np],SM[np],SQ[np]);
    else if (j&1)
      k_conv<2><<<GB,256,0,stream>>>(Tb, nullptr, Wm, convb+j*128, uj, cj, L, seg, wp,
          SZ[rp],SWt[rp],SM[rp],SQ[rp],
          SZ[wp_],SWt[wp_],SM[wp_],SQ[wp_], SZ[np],SWt[np],SM[np],SQ[np]);
    else
      k_conv<3><<<GB,256,0,stream>>>(Tb, A0, Wm, convb+j*128, uj, cj, L, seg, wp,
          SZ[rp],SWt[rp],SM[rp],SQ[rp],
          SZ[wp_],SWt[wp_],SM[wp_],SQ[wp_], SZ[np],SWt[np],SM[np],SQ[np]);
  }

  k_megaout<<<GB,256,0,stream>>>(Tb, A0, Wf+(size_t)16*16384, outb, seg, L,
                                 SZ[2],SWt[2],SM[2],SQ[2], Of, a_out);
}